// Round 17
// baseline (533.923 us; speedup 1.0000x reference)
//
#include <hip/hip_runtime.h>

namespace {

constexpr int kNodes = 4000;        // node-TYPE vocabulary (attn/alpha space)
constexpr int kRels  = 400;
constexpr int kB     = 32;
constexpr int kV     = 20;
constexpr int kN     = 32000;       // graph nodes (CSR space)
constexpr int kE     = 256000;
constexpr int kH     = 128;
constexpr int kL     = 3;
constexpr int kMPad  = 4096;        // alpha_w m-dim padded (output tiling)
constexpr int kKW    = 4000;        // true K
constexpr int kKP    = 4096;        // K padded (zeros) -> 4 slices x 1024, BK=32
constexpr int kZS    = 4;           // K slices
constexpr int kBV    = kB * kV;     // 640
constexpr int kNB    = 32;          // CSR sort blocks
constexpr int kChunk = kE / kNB;    // 8000 edges per sort block
constexpr int kHalf  = 16000;       // bins per LDS pass (64KB LDS); 2*kHalf == kN
constexpr int kPSeg  = 16;          // pool segments per batch
constexpr int kESeg  = 32;          // ehr segments per batch (125 nodes each)

typedef __attribute__((ext_vector_type(8))) short bf16x8;
typedef __attribute__((ext_vector_type(4))) float f32x4;

__device__ inline unsigned short f2bf(float f){
  unsigned int u = __float_as_uint(f);
  u += 0x7FFFu + ((u >> 16) & 1u);      // round-to-nearest-even
  return (unsigned short)(u >> 16);
}
__device__ inline float bf2f(unsigned short u){
  return __uint_as_float(((unsigned int)u) << 16);
}

// global->LDS direct copy, 16B per lane, dest = wave-uniform base + lane*16
__device__ inline void gload_lds16(const unsigned short* g, unsigned short* l){
  __builtin_amdgcn_global_load_lds(
      (const __attribute__((address_space(1))) unsigned int*)(g),
      (__attribute__((address_space(3))) unsigned int*)(l),
      16, 0, 0);
}

// ---------- prep kernels ----------

__global__ void transpose_kernel(const float* __restrict__ lin_w, const float* __restrict__ nn_w,
                                 float* __restrict__ lin_wT, float* __restrict__ nn_wT){
  int m = blockIdx.x;
  const float* in = (m == 0) ? lin_w : nn_w + (size_t)(m-1)*kH*kH;
  float* out      = (m == 0) ? lin_wT : nn_wT + (size_t)(m-1)*kH*kH;
  for (int i = threadIdx.x; i < kH*kH; i += blockDim.x){
    int r = i >> 7, c = i & (kH-1);
    out[c*kH + r] = in[i];
  }
}

__global__ __launch_bounds__(128) void proj_kernel(const float* __restrict__ node_emb,
    const float* __restrict__ rel_emb, const float* __restrict__ lin_wT,
    const float* __restrict__ lin_b, float* __restrict__ emb_lin, float* __restrict__ rel_lin){
  int row = blockIdx.x;
  const float* src; float* dst;
  if (row < kNodes){ src = node_emb + (size_t)row*kH; dst = emb_lin + (size_t)row*kH; }
  else             { src = rel_emb + (size_t)(row-kNodes)*kH; dst = rel_lin + (size_t)(row-kNodes)*kH; }
  __shared__ float rs[kH];
  int h = threadIdx.x;
  rs[h] = src[h];
  __syncthreads();
  float acc = lin_b[h];
#pragma unroll 8
  for (int k = 0; k < kH; k++) acc = fmaf(rs[k], lin_wT[k*kH + h], acc);
  dst[h] = acc;
}

__global__ void gather_x0_kernel(const int* __restrict__ node_ids,
                                 const float* __restrict__ emb_lin, float* __restrict__ x,
                                 unsigned short* __restrict__ xbf){
  int idx = blockIdx.x*256 + threadIdx.x;
  if (idx < kN*kH){
    int i = idx >> 7, c = idx & (kH-1);
    float v = emb_lin[(size_t)node_ids[i]*kH + c];
    x[idx] = v;
    xbf[idx] = f2bf(v);
  }
}

__global__ __launch_bounds__(128) void relterm_kernel(const float* __restrict__ rel_lin,
    const float* __restrict__ wr_w, const float* __restrict__ wr_b, float* __restrict__ relterm){
  int l = blockIdx.x / kRels, r = blockIdx.x % kRels;
  int t = threadIdx.x;
  float rl = rel_lin[(size_t)r*kH + t];
  __shared__ float red[kH];
  red[t] = rl * wr_w[l*kH + t];
  __syncthreads();
  for (int o = 64; o > 0; o >>= 1){
    if (t < o) red[t] += red[t+o];
    __syncthreads();
  }
  float w = red[0] + wr_b[l];
  relterm[((size_t)l*kRels + r)*kH + t] = w * rl;
}

// ---------- CSR build over kN graph nodes (no global atomics) ----------

__global__ __launch_bounds__(256) void csr_hist_kernel(const int* __restrict__ dst,
    unsigned short* __restrict__ rank, unsigned int* __restrict__ hpart){
  __shared__ unsigned int hb[kHalf];
  int p = blockIdx.x;
  int base = blockIdx.y * kHalf;
  int t = threadIdx.x;
  for (int i = t; i < kHalf; i += 256) hb[i] = 0u;
  __syncthreads();
  for (int i = t; i < kChunk; i += 256){
    int e = p*kChunk + i;
    int d = dst[e];
    int rel = d - base;
    if ((unsigned)rel < (unsigned)kHalf){
      rank[e] = (unsigned short)atomicAdd(&hb[rel], 1u);
    }
  }
  __syncthreads();
  for (int i = t; i < kHalf; i += 256)
    hpart[(size_t)p*kN + base + i] = hb[i];
}

__global__ __launch_bounds__(256) void csr_col_kernel(unsigned int* __restrict__ hpart,
    int* __restrict__ deg){
  int bin = blockIdx.x*256 + threadIdx.x;
  if (bin >= kN) return;
  unsigned int s = 0;
#pragma unroll
  for (int p = 0; p < kNB; p++){
    size_t idx = (size_t)p*kN + bin;
    unsigned int v = hpart[idx];
    hpart[idx] = s;
    s += v;
  }
  deg[bin] = (int)s;
}

__global__ __launch_bounds__(256) void scanA_kernel(const int* __restrict__ deg,
    int* __restrict__ starts, int* __restrict__ bsum){
  __shared__ int buf[256];
  int gid = blockIdx.x*256 + threadIdx.x;
  int t = threadIdx.x;
  int v = (gid < kN) ? deg[gid] : 0;
  buf[t] = v;
  __syncthreads();
  for (int o = 1; o < 256; o <<= 1){
    int add = (t >= o) ? buf[t-o] : 0;
    __syncthreads();
    buf[t] += add;
    __syncthreads();
  }
  if (gid < kN) starts[gid] = buf[t] - v;
  if (t == 255) bsum[blockIdx.x] = buf[255];
}

// fused scanB+scanC: every block re-scans bsum in LDS, adds its own prefix
__global__ __launch_bounds__(256) void scanC_kernel(int* __restrict__ starts,
    const int* __restrict__ bsum, int nblk){
  __shared__ int buf[128];
  int t = threadIdx.x;
  if (t < 128){
    int v = (t < nblk) ? bsum[t] : 0;
    buf[t] = v;
  }
  __syncthreads();
  for (int o = 1; o < 128; o <<= 1){
    int add = 0;
    if (t < 128 && t >= o) add = buf[t-o];
    __syncthreads();
    if (t < 128) buf[t] += add;
    __syncthreads();
  }
  int boff = (blockIdx.x > 0) ? buf[blockIdx.x - 1] : 0;   // exclusive prefix
  int gid = blockIdx.x*256 + t;
  if (gid < kN) starts[gid] += boff;
  if (gid == kN-1) starts[kN] = kE;
}

// writes src/rel per edge directly in CSR order (drops one indirection in aggnn)
__global__ __launch_bounds__(256) void csr_place_kernel(const int* __restrict__ dst,
    const int* __restrict__ src, const int* __restrict__ rel_ids,
    const int* __restrict__ starts, const unsigned int* __restrict__ colOff,
    const unsigned short* __restrict__ rank,
    int* __restrict__ src_perm, int* __restrict__ rel_perm){
  int blk = blockIdx.x;                 // 128 blocks x 2000 edges
  int p = blk >> 2;                     // 4 blocks per sort chunk
  for (int i = threadIdx.x; i < 2000; i += 256){
    int e = blk*2000 + i;
    int d = dst[e];
    int pos = starts[d] + (int)colOff[(size_t)p*kN + d] + (int)rank[e];
    src_perm[pos] = src[e];
    rel_perm[pos] = rel_ids[e];
  }
}

__global__ void ub_kernel(const int* __restrict__ batch, int* __restrict__ ub){
  int j = threadIdx.x;
  if (j > kB) return;
  int lo = 0, hi = kN;
  while (lo < hi){
    int mid = (lo + hi) >> 1;
    if (batch[mid] < j) lo = mid + 1; else hi = mid;
  }
  ub[j] = lo;
}

// ---------- attention path ----------

// fused: visit row -> bf16 row (K padded to 4096 with zeros) + 3 beta dots
__global__ __launch_bounds__(256) void visit_prep_kernel(const float* __restrict__ visit,
    const float* __restrict__ beta_w, const float* __restrict__ beta_b,
    unsigned short* __restrict__ visitbf, float* __restrict__ beta){
  int bv = blockIdx.x;
  int t = threadIdx.x;
  const float* row = visit + (size_t)bv*kKW;
  unsigned short* outr = visitbf + (size_t)bv*kKP;
  float d0 = 0.f, d1 = 0.f, d2 = 0.f;
  for (int i = t; i < kKP/4; i += 256){
    if (i*4 < kKW){
      float4 v = *reinterpret_cast<const float4*>(row + i*4);
      unsigned int lo = ((unsigned int)f2bf(v.y) << 16) | f2bf(v.x);
      unsigned int hi = ((unsigned int)f2bf(v.w) << 16) | f2bf(v.z);
      *reinterpret_cast<uint2*>(outr + i*4) = uint2{lo, hi};
      float4 w0 = *reinterpret_cast<const float4*>(beta_w + i*4);
      float4 w1 = *reinterpret_cast<const float4*>(beta_w + kKW + i*4);
      float4 w2 = *reinterpret_cast<const float4*>(beta_w + 2*kKW + i*4);
      d0 = fmaf(v.x,w0.x, fmaf(v.y,w0.y, fmaf(v.z,w0.z, fmaf(v.w,w0.w, d0))));
      d1 = fmaf(v.x,w1.x, fmaf(v.y,w1.y, fmaf(v.z,w1.z, fmaf(v.w,w1.w, d1))));
      d2 = fmaf(v.x,w2.x, fmaf(v.y,w2.y, fmaf(v.z,w2.z, fmaf(v.w,w2.w, d2))));
    } else {
      *reinterpret_cast<uint2*>(outr + i*4) = uint2{0u, 0u};
    }
  }
#pragma unroll
  for (int o = 32; o > 0; o >>= 1){
    d0 += __shfl_down(d0, o);
    d1 += __shfl_down(d1, o);
    d2 += __shfl_down(d2, o);
  }
  __shared__ float part[3][4];
  int wv = t >> 6, ln = t & 63;
  if (ln == 0){ part[0][wv] = d0; part[1][wv] = d1; part[2][wv] = d2; }
  __syncthreads();
  if (t < 3){
    float s = part[t][0] + part[t][1] + part[t][2] + part[t][3];
    int v = bv % kV;
    float lam = __expf(0.03f * (float)(kV - v));
    beta[t*kBV + bv] = tanhf(s + beta_b[t]) * lam;
  }
}

// all 3 layers of alpha_w (4000x4000 f32) -> (4096 x 4096 bf16), pads zeroed
__global__ void cvtW_kernel(const float* __restrict__ W, unsigned short* __restrict__ out){
  int i = blockIdx.x*256 + threadIdx.x;
  constexpr int perL = kMPad*(kKP/8);
  if (i >= kL*perL) return;
  int l = i / perL;
  int rem = i - l*perL;
  int row = rem / (kKP/8);
  int col = (rem - row*(kKP/8)) * 8;
  unsigned short r[8];
  if (row < kNodes && col < kKW){
    const float* p = W + (size_t)l*kNodes*kNodes + (size_t)row*kKW + col;
    const float4 a = *reinterpret_cast<const float4*>(p);
    const float4 b = *reinterpret_cast<const float4*>(p + 4);
    r[0]=f2bf(a.x); r[1]=f2bf(a.y); r[2]=f2bf(a.z); r[3]=f2bf(a.w);
    r[4]=f2bf(b.x); r[5]=f2bf(b.y); r[6]=f2bf(b.z); r[7]=f2bf(b.w);
  } else {
    for (int q = 0; q < 8; q++) r[q] = 0;
  }
  *reinterpret_cast<uint4*>(out + (size_t)l*kMPad*kKP + (size_t)row*kKP + col)
      = *reinterpret_cast<uint4*>(r);
}

// S[lz](640 x 4096, bf16) = A(640 x 1024-slice) @ B_l(4096 x 1024-slice)^T
// lz = l*4+z, grid 1920 (7.5 blocks/CU queued vs 5 LDS capacity -> better
// occupancy than r16's 960/3.75). r8 inner structure verbatim: BK=32 dbuf,
// depth-1 prefetch, 0-conflict both-sides swizzle, XCD-chunked block swizzle.
__global__ __launch_bounds__(256) void gemm_bt_bf16(const unsigned short* __restrict__ A,
    const unsigned short* __restrict__ Ball, unsigned short* __restrict__ Sbase){
  __shared__ unsigned short As[2][128*32];
  __shared__ unsigned short Bs[2][128*32];
  // 1920 blocks; chunk = 240 per XCD
  int wg = (blockIdx.x & 7)*240 + (blockIdx.x >> 3);
  int lz = wg / 160;
  int rem = wg - lz*160;
  int bn = rem / 5;
  int bm = rem - bn*5;
  int l = lz >> 2, z = lz & 3;
  const unsigned short* B = Ball + (size_t)l*kMPad*kKP;
  unsigned short* C = Sbase + (size_t)lz*kBV*kMPad;
  int kBase = z * (kKP/kZS);            // 1024 per slice
  constexpr int nt = (kKP/kZS) / 32;    // 32 tiles

  int t = threadIdx.x;
  int lane = t & 63, wave = t >> 6;
  int wm = (wave >> 1) * 64, wn = (wave & 1) * 64;
  int r = lane & 15, g = lane >> 4;

  int ri = lane >> 2, s = lane & 3;
  int koff = ((s ^ ((ri >> 1) & 3)) << 3);   // elements
  const unsigned short* Ag = A + (size_t)(bm*128 + wave*32 + ri)*kKP + kBase + koff;
  const unsigned short* Bg = B + (size_t)(bn*128 + wave*32 + ri)*kKP + kBase + koff;
  const size_t rstep = (size_t)16*kKP;       // 16 rows

  f32x4 acc[4][4];
#pragma unroll
  for (int i = 0; i < 4; i++)
#pragma unroll
    for (int j = 0; j < 4; j++) acc[i][j] = f32x4{0.f,0.f,0.f,0.f};

  auto STAGE = [&](int buf, int ts){
    const unsigned short* a = Ag + ts*32;
    const unsigned short* b = Bg + ts*32;
    gload_lds16(a,         &As[buf][(wave*32     )*32]);
    gload_lds16(a + rstep, &As[buf][(wave*32 + 16)*32]);
    gload_lds16(b,         &Bs[buf][(wave*32     )*32]);
    gload_lds16(b + rstep, &Bs[buf][(wave*32 + 16)*32]);
  };

  STAGE(0, 0);
  for (int ts = 0; ts < nt; ts++){
    int cur = ts & 1;
    __syncthreads();                   // drains vmcnt: STAGE(ts) landed for all waves
    if (ts + 1 < nt) STAGE(cur ^ 1, ts + 1);   // prefetch overlaps this tile's compute
    bf16x8 af[4], bf[4];
#pragma unroll
    for (int i = 0; i < 4; i++){
      int arow = wm + i*16 + r;
      int brow = wn + i*16 + r;
      af[i] = *reinterpret_cast<const bf16x8*>(
          &As[cur][arow*32 + ((g ^ ((arow >> 1) & 3)) << 3)]);
      bf[i] = *reinterpret_cast<const bf16x8*>(
          &Bs[cur][brow*32 + ((g ^ ((brow >> 1) & 3)) << 3)]);
    }
#pragma unroll
    for (int i = 0; i < 4; i++)
#pragma unroll
      for (int j = 0; j < 4; j++)
        acc[i][j] = __builtin_amdgcn_mfma_f32_16x16x32_bf16(af[i], bf[j], acc[i][j], 0, 0, 0);
  }
#pragma unroll
  for (int i = 0; i < 4; i++)
#pragma unroll
    for (int j = 0; j < 4; j++){
      int row = bm*128 + wm + i*16 + g*4;
      int col = bn*128 + wn + j*16 + r;
#pragma unroll
      for (int q = 0; q < 4; q++)
        C[(size_t)(row + q)*kMPad + col] = f2bf(acc[i][j][q]);
    }
}

// attn[l][b][m] = sum_v softmax_v(sum_z Sz) * beta[l,b,v]  (all layers; S bf16)
__global__ __launch_bounds__(256) void attn_kernel(const unsigned short* __restrict__ S,
    const float* __restrict__ beta, float* __restrict__ attn){
  int idx = blockIdx.x*256 + threadIdx.x;
  if (idx >= kL*kB*kNodes) return;
  int l = idx / (kB*kNodes);
  int rem = idx - l*(kB*kNodes);
  int b = rem / kNodes;
  int m = rem - b*kNodes;
  const unsigned short* S0 = S + (size_t)(l*kZS)*kBV*kMPad + (size_t)b*kV*kMPad + m;
  float vals[kV];
  float mx = -1e30f;
#pragma unroll
  for (int v = 0; v < kV; v++){
    size_t off = (size_t)v*kMPad;
    float s = bf2f(S0[off]);
#pragma unroll
    for (int z = 1; z < kZS; z++)
      s += bf2f(S0[(size_t)z*kBV*kMPad + off]);
    vals[v] = s; mx = fmaxf(mx, s);
  }
  float se = 0.f, ws = 0.f;
  const float* bp = beta + l*kBV + b*kV;
#pragma unroll
  for (int v = 0; v < kV; v++){ float e = __expf(vals[v] - mx); se += e; ws = fmaf(e, bp[v], ws); }
  attn[idx] = ws / se;
}

// att_e[l][p] = attn[l][batch[s]][node_ids[s]], s = src_perm[p] (perm-ordered, all layers)
__global__ void att_e_kernel(const int* __restrict__ src_perm, const int* __restrict__ batch,
    const int* __restrict__ node_ids, const float* __restrict__ attn,
    float* __restrict__ att_e){
  int idx = blockIdx.x*256 + threadIdx.x;
  if (idx >= kL*kE) return;
  int l = idx / kE, p = idx - l*kE;
  int s = src_perm[p];
  att_e[idx] = attn[(size_t)l*kB*kNodes + (size_t)batch[s]*kNodes + node_ids[s]];
}

// ---------- GNN layer: fused aggregate + nn (512 threads = 8 waves, 8 nodes/block) ----------
// r13-proven version: 1 wave/node, 2-stage pipeline on the edge loop.

__global__ __launch_bounds__(512) void aggnn_kernel(const int* __restrict__ starts,
    const int* __restrict__ src_perm, const int* __restrict__ rel_perm,
    const float* __restrict__ att_e_l, const float* __restrict__ relterm_l,
    const unsigned short* __restrict__ xbf_in, unsigned short* __restrict__ xbf_out,
    float* __restrict__ x, const float* __restrict__ nn_wT_l, const float* __restrict__ nn_b_l){
  __shared__ float rows[8][kH];
  int t = threadIdx.x;
  int wv = t >> 6, lane = t & 63;
  int node = blockIdx.x*8 + wv;
  int p0 = starts[node], p1 = starts[node+1];
  int c = lane*2;
  float a0 = 0.f, a1 = 0.f;

  float at_c = 0.f;
  unsigned int xv_c = 0u;
  float2 rt_c = float2{0.f, 0.f};
  if (p0 < p1){
    int s0 = src_perm[p0], r0 = rel_perm[p0];
    at_c = att_e_l[p0];
    xv_c = *reinterpret_cast<const unsigned int*>(&xbf_in[(size_t)s0*kH + c]);
    rt_c = *reinterpret_cast<const float2*>(&relterm_l[(size_t)r0*kH + c]);
  }
  for (int p = p0; p < p1; p++){
    float at_n = 0.f;
    unsigned int xv_n = 0u;
    float2 rt_n = float2{0.f, 0.f};
    if (p + 1 < p1){
      int sn = src_perm[p+1], rn = rel_perm[p+1];
      at_n = att_e_l[p+1];
      xv_n = *reinterpret_cast<const unsigned int*>(&xbf_in[(size_t)sn*kH + c]);
      rt_n = *reinterpret_cast<const float2*>(&relterm_l[(size_t)rn*kH + c]);
    }
    float x0 = __uint_as_float(xv_c << 16);            // low bf16
    float x1 = __uint_as_float(xv_c & 0xFFFF0000u);    // high bf16
    float m0 = fmaf(x0, at_c, rt_c.x); m0 = m0 > 0.f ? m0 : 0.f;
    float m1 = fmaf(x1, at_c, rt_c.y); m1 = m1 > 0.f ? m1 : 0.f;
    a0 += m0; a1 += m1;
    at_c = at_n; xv_c = xv_n; rt_c = rt_n;
  }
  size_t gi = (size_t)node*kH + c;
  rows[wv][c]   = a0 + x[gi];
  rows[wv][c+1] = a1 + x[gi+1];
  __syncthreads();
  int cc = t & 127;
  int r0 = (t >> 7) * 2;                 // rows {0,1},{2,3},{4,5},{6,7}
  float acc0 = 0.f, acc1 = 0.f;
#pragma unroll 8
  for (int k = 0; k < kH; k++){
    float w = nn_wT_l[k*kH + cc];
    acc0 = fmaf(rows[r0  ][k], w, acc0);
    acc1 = fmaf(rows[r0+1][k], w, acc1);
  }
  float b = nn_b_l[cc];
  float o0 = fmaxf(acc0 + b, 0.f);
  float o1 = fmaxf(acc1 + b, 0.f);
  size_t n0 = (size_t)(blockIdx.x*8 + r0)*kH + cc;
  x[n0]        = o0;  xbf_out[n0]        = f2bf(o0);
  x[n0 + kH]   = o1;  xbf_out[n0 + kH]   = f2bf(o1);
}

// ---------- readout (fused; no atomics; HIGH PARALLELISM) ----------
// s<16: pool partial over 1/16 batch segment; s in [16,48): ehr*node_emb
// partial over 125 nodes. 1536 blocks total -> ~6 blocks/CU, latency hidden.
__global__ __launch_bounds__(128) void readprep_kernel(const float* __restrict__ x,
    const int* __restrict__ ub, const float* __restrict__ ehr,
    const float* __restrict__ node_emb, float* __restrict__ pp,
    float* __restrict__ pn, float* __restrict__ ps){
  int s = blockIdx.x, b = blockIdx.y, c = threadIdx.x;
  if (s < kPSeg){
    int lo = ub[b], len = ub[b+1] - lo;
    int i0 = lo + (int)(((long long)len * s) / kPSeg);
    int i1 = lo + (int)(((long long)len * (s+1)) / kPSeg);
    float acc = 0.f;
    for (int i = i0; i < i1; i++) acc += x[(size_t)i*kH + c];
    pp[(size_t)(b*kPSeg + s)*kH + c] = acc;
  } else {
    int q = s - kPSeg;                       // 0..31
    constexpr int seg = kNodes/kESeg;        // 125
    int n0 = q * seg;
    const float* ep = ehr + (size_t)b*kNodes + n0;
    const float* ne = node_emb + (size_t)n0*kH + c;
    float acc0 = 0.f, acc1 = 0.f, es = 0.f;
#pragma unroll 4
    for (int n = 0; n < seg - 1; n += 2){    // pairs (0,1)..(122,123)
      float e0 = ep[n], e1 = ep[n+1];
      es += e0 + e1;
      acc0 = fmaf(e0, ne[(size_t)n*kH], acc0);
      acc1 = fmaf(e1, ne[(size_t)(n+1)*kH], acc1);
    }
    {                                        // odd tail: n = 124 only
      float e0 = ep[seg - 1];
      es += e0;
      acc0 = fmaf(e0, ne[(size_t)(seg - 1)*kH], acc0);
    }
    pn[(size_t)(b*kESeg + q)*kH + c] = acc0 + acc1;
    if (c == 0) ps[b*kESeg + q] = es;
  }
}

// xg-finish + xnode-finish + final MLP in one kernel
__global__ __launch_bounds__(128) void readout_kernel(const float* __restrict__ pp,
    const int* __restrict__ ub, const float* __restrict__ pn, const float* __restrict__ ps,
    const float* __restrict__ lin_wT, const float* __restrict__ lin_b,
    const float* __restrict__ mlp_w, const float* __restrict__ mlp_b,
    float* __restrict__ out){
  int b = blockIdx.x, h = threadIdx.x;
  __shared__ float v[2*kH];
  __shared__ float ts[kH];
  float s = 0.f;
#pragma unroll
  for (int q = 0; q < kPSeg; q++) s += pp[(size_t)(b*kPSeg + q)*kH + h];
  int len = ub[b+1] - ub[b]; if (len < 1) len = 1;
  v[h] = s / (float)len;
  float acc = 0.f, es = 0.f;
#pragma unroll
  for (int q = 0; q < kESeg; q++){
    acc += pn[(size_t)(b*kESeg + q)*kH + h];
    es  += ps[b*kESeg + q];
  }
  ts[h] = acc / es;
  __syncthreads();
  float r = lin_b[h];
#pragma unroll 8
  for (int k = 0; k < kH; k++) r = fmaf(ts[k], lin_wT[k*kH + h], r);
  v[kH + h] = r;
  __syncthreads();
  float o = mlp_b[h];
#pragma unroll 8
  for (int k = 0; k < 2*kH; k++) o = fmaf(v[k], mlp_w[(size_t)h*2*kH + k], o);
  out[b*kH + h] = o;
}

} // namespace

extern "C" void kernel_launch(void* const* d_in, const int* in_sizes, int n_in,
                              void* d_out, int out_size, void* d_ws, size_t ws_size,
                              hipStream_t stream){
  const int*   node_ids = (const int*)d_in[0];
  const int*   rel_ids  = (const int*)d_in[1];
  const int*   e_src    = (const int*)d_in[2];
  const int*   e_dst    = e_src + kE;
  const int*   batch    = (const int*)d_in[3];
  const float* visit    = (const float*)d_in[4];
  const float* ehr      = (const float*)d_in[5];
  const float* node_emb = (const float*)d_in[6];
  const float* rel_emb  = (const float*)d_in[7];
  const float* lin_w    = (const float*)d_in[8];
  const float* lin_b    = (const float*)d_in[9];
  const float* alpha_w  = (const float*)d_in[10];
  const float* beta_w   = (const float*)d_in[12];
  const float* beta_b   = (const float*)d_in[13];
  const float* wr_w     = (const float*)d_in[14];
  const float* wr_b     = (const float*)d_in[15];
  const float* nn_w     = (const float*)d_in[16];
  const float* nn_b     = (const float*)d_in[17];
  const float* mlp_w    = (const float*)d_in[18];
  const float* mlp_b    = (const float*)d_in[19];
  float* out = (float*)d_out;

  char* w = (char*)d_ws;
  auto alloc = [&](size_t bytes)->char*{
    char* p = w; w += (bytes + 255) & ~(size_t)255; return p;
  };
  int*   starts = (int*)  alloc((size_t)(kN+1)*4);
  int*   deg    = (int*)  alloc((size_t)kN*4);
  int*   bsum   = (int*)  alloc(256*4);
  int*   ub     = (int*)  alloc((kB+1)*4);
  int*   src_perm = (int*)alloc((size_t)kE*4);
  int*   rel_perm = (int*)alloc((size_t)kE*4);
  unsigned short* rank = (unsigned short*)alloc((size_t)kE*2);
  unsigned int* hpart  = (unsigned int*)alloc((size_t)kNB*kN*4);   // becomes colOff in place
  float* embLin = (float*)alloc((size_t)kNodes*kH*4);
  float* relLin = (float*)alloc((size_t)kRels*kH*4);
  float* relterm= (float*)alloc((size_t)kL*kRels*kH*4);
  float* linwT  = (float*)alloc((size_t)kH*kH*4);
  float* nnwT   = (float*)alloc((size_t)kL*kH*kH*4);
  float* x      = (float*)alloc((size_t)kN*kH*4);
  unsigned short* xbfA = (unsigned short*)alloc((size_t)kN*kH*2);
  unsigned short* xbfB = (unsigned short*)alloc((size_t)kN*kH*2);
  unsigned short* visitbf = (unsigned short*)alloc((size_t)kBV*kKP*2);
  unsigned short* awbf    = (unsigned short*)alloc((size_t)kL*kMPad*kKP*2);
  unsigned short* S       = (unsigned short*)alloc((size_t)kL*kZS*kBV*kMPad*2);
  float* attn   = (float*)alloc((size_t)kL*kB*kNodes*4);
  float* att_e  = (float*)alloc((size_t)kL*kE*4);
  float* beta   = (float*)alloc((size_t)kL*kBV*4);
  float* pp     = (float*)alloc((size_t)kB*kPSeg*kH*4);
  float* pn     = (float*)alloc((size_t)kB*kESeg*kH*4);
  float* ps     = (float*)alloc((size_t)kB*kESeg*4);
  if ((size_t)(w - (char*)d_ws) > ws_size) return;   // ws too small: fail visibly

  // prep
  transpose_kernel<<<4, 256, 0, stream>>>(lin_w, nn_w, linwT, nnwT);
  proj_kernel<<<kNodes + kRels, 128, 0, stream>>>(node_emb, rel_emb, linwT, lin_b, embLin, relLin);
  gather_x0_kernel<<<(kN*kH)/256, 256, 0, stream>>>(node_ids, embLin, x, xbfA);
  relterm_kernel<<<kL*kRels, 128, 0, stream>>>(relLin, wr_w, wr_b, relterm);

  // CSR build (no global atomics)
  csr_hist_kernel<<<dim3(kNB, 2), 256, 0, stream>>>(e_dst, rank, hpart);
  csr_col_kernel<<<(kN+255)/256, 256, 0, stream>>>(hpart, deg);
  scanA_kernel<<<(kN+255)/256, 256, 0, stream>>>(deg, starts, bsum);
  scanC_kernel<<<(kN+255)/256, 256, 0, stream>>>(starts, bsum, (kN+255)/256);
  csr_place_kernel<<<128, 256, 0, stream>>>(e_dst, e_src, rel_ids, starts, hpart, rank,
                                            src_perm, rel_perm);
  ub_kernel<<<1, 64, 0, stream>>>(batch, ub);

  // attention path (all layers batched)
  visit_prep_kernel<<<kBV, 256, 0, stream>>>(visit, beta_w, beta_b, visitbf, beta);
  cvtW_kernel<<<(kL*kMPad*(kKP/8) + 255)/256, 256, 0, stream>>>(alpha_w, awbf);
  gemm_bt_bf16<<<1920, 256, 0, stream>>>(visitbf, awbf, S);
  attn_kernel<<<(kL*kB*kNodes + 255)/256, 256, 0, stream>>>(S, beta, attn);
  att_e_kernel<<<(kL*kE + 255)/256, 256, 0, stream>>>(src_perm, batch, node_ids, attn, att_e);

  // GNN layers (fused aggregate+nn; xbf ping-pong, x f32 block-local in-place)
  unsigned short* xin = xbfA;
  unsigned short* xout = xbfB;
  for (int l = 0; l < kL; l++){
    aggnn_kernel<<<kN/8, 512, 0, stream>>>(starts, src_perm, rel_perm,
        att_e + (size_t)l*kE, relterm + (size_t)l*kRels*kH,
        xin, xout, x, nnwT + (size_t)l*kH*kH, nn_b + (size_t)l*kH);
    unsigned short* tmp = xin; xin = xout; xout = tmp;
  }

  // readout
  readprep_kernel<<<dim3(kPSeg + kESeg, kB), 128, 0, stream>>>(x, ub, ehr, node_emb, pp, pn, ps);
  readout_kernel<<<kB, 128, 0, stream>>>(pp, ub, pn, ps, linwT, lin_b, mlp_w, mlp_b, out);
}

// Round 18
// 517.579 us; speedup vs baseline: 1.0316x; 1.0316x over previous
//
#include <hip/hip_runtime.h>

namespace {

constexpr int kNodes = 4000;        // node-TYPE vocabulary (attn/alpha space)
constexpr int kRels  = 400;
constexpr int kB     = 32;
constexpr int kV     = 20;
constexpr int kN     = 32000;       // graph nodes (CSR space)
constexpr int kE     = 256000;
constexpr int kH     = 128;
constexpr int kL     = 3;
constexpr int kMPad  = 4096;        // alpha_w m-dim padded (output tiling)
constexpr int kKW    = 4000;        // K exact: 125 x BK=32
constexpr int kBV    = kB * kV;     // 640
constexpr int kNB    = 32;          // CSR sort blocks
constexpr int kChunk = kE / kNB;    // 8000 edges per sort block
constexpr int kHalf  = 16000;       // bins per LDS pass (64KB LDS); 2*kHalf == kN
constexpr int kPSeg  = 16;          // pool segments per batch
constexpr int kESeg  = 32;          // ehr segments per batch (125 nodes each)

typedef __attribute__((ext_vector_type(8))) short bf16x8;
typedef __attribute__((ext_vector_type(4))) float f32x4;

__device__ inline unsigned short f2bf(float f){
  unsigned int u = __float_as_uint(f);
  u += 0x7FFFu + ((u >> 16) & 1u);      // round-to-nearest-even
  return (unsigned short)(u >> 16);
}
__device__ inline float bf2f(unsigned short u){
  return __uint_as_float(((unsigned int)u) << 16);
}

// global->LDS direct copy, 16B per lane, dest = wave-uniform base + lane*16
__device__ inline void gload_lds16(const unsigned short* g, unsigned short* l){
  __builtin_amdgcn_global_load_lds(
      (const __attribute__((address_space(1))) unsigned int*)(g),
      (__attribute__((address_space(3))) unsigned int*)(l),
      16, 0, 0);
}

// ---------- prep kernels ----------

__global__ void transpose_kernel(const float* __restrict__ lin_w, const float* __restrict__ nn_w,
                                 float* __restrict__ lin_wT, float* __restrict__ nn_wT){
  int m = blockIdx.x;
  const float* in = (m == 0) ? lin_w : nn_w + (size_t)(m-1)*kH*kH;
  float* out      = (m == 0) ? lin_wT : nn_wT + (size_t)(m-1)*kH*kH;
  for (int i = threadIdx.x; i < kH*kH; i += blockDim.x){
    int r = i >> 7, c = i & (kH-1);
    out[c*kH + r] = in[i];
  }
}

__global__ __launch_bounds__(128) void proj_kernel(const float* __restrict__ node_emb,
    const float* __restrict__ rel_emb, const float* __restrict__ lin_wT,
    const float* __restrict__ lin_b, float* __restrict__ emb_lin, float* __restrict__ rel_lin){
  int row = blockIdx.x;
  const float* src; float* dst;
  if (row < kNodes){ src = node_emb + (size_t)row*kH; dst = emb_lin + (size_t)row*kH; }
  else             { src = rel_emb + (size_t)(row-kNodes)*kH; dst = rel_lin + (size_t)(row-kNodes)*kH; }
  __shared__ float rs[kH];
  int h = threadIdx.x;
  rs[h] = src[h];
  __syncthreads();
  float acc = lin_b[h];
#pragma unroll 8
  for (int k = 0; k < kH; k++) acc = fmaf(rs[k], lin_wT[k*kH + h], acc);
  dst[h] = acc;
}

__global__ void gather_x0_kernel(const int* __restrict__ node_ids,
                                 const float* __restrict__ emb_lin, float* __restrict__ x,
                                 unsigned short* __restrict__ xbf){
  int idx = blockIdx.x*256 + threadIdx.x;
  if (idx < kN*kH){
    int i = idx >> 7, c = idx & (kH-1);
    float v = emb_lin[(size_t)node_ids[i]*kH + c];
    x[idx] = v;
    xbf[idx] = f2bf(v);
  }
}

__global__ __launch_bounds__(128) void relterm_kernel(const float* __restrict__ rel_lin,
    const float* __restrict__ wr_w, const float* __restrict__ wr_b, float* __restrict__ relterm){
  int l = blockIdx.x / kRels, r = blockIdx.x % kRels;
  int t = threadIdx.x;
  float rl = rel_lin[(size_t)r*kH + t];
  __shared__ float red[kH];
  red[t] = rl * wr_w[l*kH + t];
  __syncthreads();
  for (int o = 64; o > 0; o >>= 1){
    if (t < o) red[t] += red[t+o];
    __syncthreads();
  }
  float w = red[0] + wr_b[l];
  relterm[((size_t)l*kRels + r)*kH + t] = w * rl;
}

// ---------- CSR build over kN graph nodes (no global atomics) ----------

__global__ __launch_bounds__(256) void csr_hist_kernel(const int* __restrict__ dst,
    unsigned short* __restrict__ rank, unsigned int* __restrict__ hpart){
  __shared__ unsigned int hb[kHalf];
  int p = blockIdx.x;
  int base = blockIdx.y * kHalf;
  int t = threadIdx.x;
  for (int i = t; i < kHalf; i += 256) hb[i] = 0u;
  __syncthreads();
  for (int i = t; i < kChunk; i += 256){
    int e = p*kChunk + i;
    int d = dst[e];
    int rel = d - base;
    if ((unsigned)rel < (unsigned)kHalf){
      rank[e] = (unsigned short)atomicAdd(&hb[rel], 1u);
    }
  }
  __syncthreads();
  for (int i = t; i < kHalf; i += 256)
    hpart[(size_t)p*kN + base + i] = hb[i];
}

__global__ __launch_bounds__(256) void csr_col_kernel(unsigned int* __restrict__ hpart,
    int* __restrict__ deg){
  int bin = blockIdx.x*256 + threadIdx.x;
  if (bin >= kN) return;
  unsigned int s = 0;
#pragma unroll
  for (int p = 0; p < kNB; p++){
    size_t idx = (size_t)p*kN + bin;
    unsigned int v = hpart[idx];
    hpart[idx] = s;
    s += v;
  }
  deg[bin] = (int)s;
}

__global__ __launch_bounds__(256) void scanA_kernel(const int* __restrict__ deg,
    int* __restrict__ starts, int* __restrict__ bsum){
  __shared__ int buf[256];
  int gid = blockIdx.x*256 + threadIdx.x;
  int t = threadIdx.x;
  int v = (gid < kN) ? deg[gid] : 0;
  buf[t] = v;
  __syncthreads();
  for (int o = 1; o < 256; o <<= 1){
    int add = (t >= o) ? buf[t-o] : 0;
    __syncthreads();
    buf[t] += add;
    __syncthreads();
  }
  if (gid < kN) starts[gid] = buf[t] - v;
  if (t == 255) bsum[blockIdx.x] = buf[255];
}

// fused scanB+scanC: every block re-scans bsum in LDS, adds its own prefix
__global__ __launch_bounds__(256) void scanC_kernel(int* __restrict__ starts,
    const int* __restrict__ bsum, int nblk){
  __shared__ int buf[128];
  int t = threadIdx.x;
  if (t < 128){
    int v = (t < nblk) ? bsum[t] : 0;
    buf[t] = v;
  }
  __syncthreads();
  for (int o = 1; o < 128; o <<= 1){
    int add = 0;
    if (t < 128 && t >= o) add = buf[t-o];
    __syncthreads();
    if (t < 128) buf[t] += add;
    __syncthreads();
  }
  int boff = (blockIdx.x > 0) ? buf[blockIdx.x - 1] : 0;   // exclusive prefix
  int gid = blockIdx.x*256 + t;
  if (gid < kN) starts[gid] += boff;
  if (gid == kN-1) starts[kN] = kE;
}

// writes src/rel per edge directly in CSR order (drops one indirection in aggnn)
__global__ __launch_bounds__(256) void csr_place_kernel(const int* __restrict__ dst,
    const int* __restrict__ src, const int* __restrict__ rel_ids,
    const int* __restrict__ starts, const unsigned int* __restrict__ colOff,
    const unsigned short* __restrict__ rank,
    int* __restrict__ src_perm, int* __restrict__ rel_perm){
  int blk = blockIdx.x;                 // 128 blocks x 2000 edges
  int p = blk >> 2;                     // 4 blocks per sort chunk
  for (int i = threadIdx.x; i < 2000; i += 256){
    int e = blk*2000 + i;
    int d = dst[e];
    int pos = starts[d] + (int)colOff[(size_t)p*kN + d] + (int)rank[e];
    src_perm[pos] = src[e];
    rel_perm[pos] = rel_ids[e];
  }
}

__global__ void ub_kernel(const int* __restrict__ batch, int* __restrict__ ub){
  int j = threadIdx.x;
  if (j > kB) return;
  int lo = 0, hi = kN;
  while (lo < hi){
    int mid = (lo + hi) >> 1;
    if (batch[mid] < j) lo = mid + 1; else hi = mid;
  }
  ub[j] = lo;
}

// ---------- attention path ----------

// fused: visit row -> bf16 row + all 3 layers' beta dot products (visit read ONCE)
__global__ __launch_bounds__(256) void visit_prep_kernel(const float* __restrict__ visit,
    const float* __restrict__ beta_w, const float* __restrict__ beta_b,
    unsigned short* __restrict__ visitbf, float* __restrict__ beta){
  int bv = blockIdx.x;
  int t = threadIdx.x;
  const float* row = visit + (size_t)bv*kKW;
  unsigned short* outr = visitbf + (size_t)bv*kKW;
  float d0 = 0.f, d1 = 0.f, d2 = 0.f;
  for (int i = t; i < kKW/4; i += 256){
    float4 v = *reinterpret_cast<const float4*>(row + i*4);
    unsigned int lo = ((unsigned int)f2bf(v.y) << 16) | f2bf(v.x);
    unsigned int hi = ((unsigned int)f2bf(v.w) << 16) | f2bf(v.z);
    *reinterpret_cast<uint2*>(outr + i*4) = uint2{lo, hi};
    float4 w0 = *reinterpret_cast<const float4*>(beta_w + i*4);
    float4 w1 = *reinterpret_cast<const float4*>(beta_w + kKW + i*4);
    float4 w2 = *reinterpret_cast<const float4*>(beta_w + 2*kKW + i*4);
    d0 = fmaf(v.x,w0.x, fmaf(v.y,w0.y, fmaf(v.z,w0.z, fmaf(v.w,w0.w, d0))));
    d1 = fmaf(v.x,w1.x, fmaf(v.y,w1.y, fmaf(v.z,w1.z, fmaf(v.w,w1.w, d1))));
    d2 = fmaf(v.x,w2.x, fmaf(v.y,w2.y, fmaf(v.z,w2.z, fmaf(v.w,w2.w, d2))));
  }
#pragma unroll
  for (int o = 32; o > 0; o >>= 1){
    d0 += __shfl_down(d0, o);
    d1 += __shfl_down(d1, o);
    d2 += __shfl_down(d2, o);
  }
  __shared__ float part[3][4];
  int wv = t >> 6, ln = t & 63;
  if (ln == 0){ part[0][wv] = d0; part[1][wv] = d1; part[2][wv] = d2; }
  __syncthreads();
  if (t < 3){
    float s = part[t][0] + part[t][1] + part[t][2] + part[t][3];
    int v = bv % kV;
    float lam = __expf(0.03f * (float)(kV - v));
    beta[t*kBV + bv] = tanhf(s + beta_b[t]) * lam;
  }
}

// all 3 layers of alpha_w (4000x4000 f32) -> (4096 x 4000 bf16), pad rows zeroed
__global__ void cvtW_kernel(const float* __restrict__ W, unsigned short* __restrict__ out){
  int i = blockIdx.x*256 + threadIdx.x;
  constexpr int perL = kMPad*(kKW/8);
  if (i >= kL*perL) return;
  int l = i / perL;
  int rem = i - l*perL;
  int row = rem / (kKW/8);
  int col = (rem - row*(kKW/8)) * 8;
  unsigned short r[8];
  if (row < kNodes){
    const float* p = W + (size_t)l*kNodes*kNodes + (size_t)row*kKW + col;
    const float4 a = *reinterpret_cast<const float4*>(p);
    const float4 b = *reinterpret_cast<const float4*>(p + 4);
    r[0]=f2bf(a.x); r[1]=f2bf(a.y); r[2]=f2bf(a.z); r[3]=f2bf(a.w);
    r[4]=f2bf(b.x); r[5]=f2bf(b.y); r[6]=f2bf(b.z); r[7]=f2bf(b.w);
  } else {
    for (int q = 0; q < 8; q++) r[q] = 0;
  }
  *reinterpret_cast<uint4*>(out + (size_t)l*kMPad*kKW + (size_t)row*kKW + col)
      = *reinterpret_cast<uint4*>(r);
}

// S[lz](640 x 4096, bf16) = A(640 x Kslice) @ B_l(4096 x Kslice)^T ; lz = l*2+z
// r16-proven structure (107-110us, total 519): BK=32 double-buffer, depth-1
// prefetch, 0-conflict both-sides swizzle, XCD-chunked block swizzle; bf16 C.
__global__ __launch_bounds__(256) void gemm_bt_bf16(const unsigned short* __restrict__ A,
    const unsigned short* __restrict__ Ball, unsigned short* __restrict__ Sbase){
  __shared__ unsigned short As[2][128*32];
  __shared__ unsigned short Bs[2][128*32];
  // 960 blocks; chunk = 120 per XCD
  int wg = (blockIdx.x & 7)*120 + (blockIdx.x >> 3);
  int lz = wg / 160;
  int rem = wg - lz*160;
  int bn = rem / 5;
  int bm = rem - bn*5;
  int l = lz >> 1, z = lz & 1;
  const unsigned short* B = Ball + (size_t)l*kMPad*kKW;
  unsigned short* C = Sbase + (size_t)lz*kBV*kMPad;
  int tile0 = z ? 63 : 0;               // 125 tiles total: 63 + 62
  int nt    = z ? 62 : 63;

  int t = threadIdx.x;
  int lane = t & 63, wave = t >> 6;
  int wm = (wave >> 1) * 64, wn = (wave & 1) * 64;
  int r = lane & 15, g = lane >> 4;

  int ri = lane >> 2, s = lane & 3;
  int koff = ((s ^ ((ri >> 1) & 3)) << 3);   // elements
  const unsigned short* Ag = A + (size_t)(bm*128 + wave*32 + ri)*kKW + tile0*32 + koff;
  const unsigned short* Bg = B + (size_t)(bn*128 + wave*32 + ri)*kKW + tile0*32 + koff;
  const size_t rstep = (size_t)16*kKW;       // 16 rows

  f32x4 acc[4][4];
#pragma unroll
  for (int i = 0; i < 4; i++)
#pragma unroll
    for (int j = 0; j < 4; j++) acc[i][j] = f32x4{0.f,0.f,0.f,0.f};

  auto STAGE = [&](int buf, int ts){
    const unsigned short* a = Ag + ts*32;
    const unsigned short* b = Bg + ts*32;
    gload_lds16(a,         &As[buf][(wave*32     )*32]);
    gload_lds16(a + rstep, &As[buf][(wave*32 + 16)*32]);
    gload_lds16(b,         &Bs[buf][(wave*32     )*32]);
    gload_lds16(b + rstep, &Bs[buf][(wave*32 + 16)*32]);
  };

  STAGE(0, 0);
  for (int ts = 0; ts < nt; ts++){
    int cur = ts & 1;
    __syncthreads();                   // drains vmcnt: STAGE(ts) landed for all waves
    if (ts + 1 < nt) STAGE(cur ^ 1, ts + 1);   // prefetch overlaps this tile's compute
    bf16x8 af[4], bf[4];
#pragma unroll
    for (int i = 0; i < 4; i++){
      int arow = wm + i*16 + r;
      int brow = wn + i*16 + r;
      af[i] = *reinterpret_cast<const bf16x8*>(
          &As[cur][arow*32 + ((g ^ ((arow >> 1) & 3)) << 3)]);
      bf[i] = *reinterpret_cast<const bf16x8*>(
          &Bs[cur][brow*32 + ((g ^ ((brow >> 1) & 3)) << 3)]);
    }
#pragma unroll
    for (int i = 0; i < 4; i++)
#pragma unroll
      for (int j = 0; j < 4; j++)
        acc[i][j] = __builtin_amdgcn_mfma_f32_16x16x32_bf16(af[i], bf[j], acc[i][j], 0, 0, 0);
  }
#pragma unroll
  for (int i = 0; i < 4; i++)
#pragma unroll
    for (int j = 0; j < 4; j++){
      int row = bm*128 + wm + i*16 + g*4;
      int col = bn*128 + wn + j*16 + r;
#pragma unroll
      for (int q = 0; q < 4; q++)
        C[(size_t)(row + q)*kMPad + col] = f2bf(acc[i][j][q]);
    }
}

// attn[l][b][m] = sum_v softmax_v(S0+S1) * beta[l,b,v]  (all layers; S is bf16)
__global__ __launch_bounds__(256) void attn_kernel(const unsigned short* __restrict__ S,
    const float* __restrict__ beta, float* __restrict__ attn){
  int idx = blockIdx.x*256 + threadIdx.x;
  if (idx >= kL*kB*kNodes) return;
  int l = idx / (kB*kNodes);
  int rem = idx - l*(kB*kNodes);
  int b = rem / kNodes;
  int m = rem - b*kNodes;
  const unsigned short* S0 = S + (size_t)(l*2)*kBV*kMPad + (size_t)b*kV*kMPad + m;
  const unsigned short* S1 = S0 + (size_t)kBV*kMPad;
  float vals[kV];
  float mx = -1e30f;
#pragma unroll
  for (int v = 0; v < kV; v++){
    float s = bf2f(S0[(size_t)v*kMPad]) + bf2f(S1[(size_t)v*kMPad]);
    vals[v] = s; mx = fmaxf(mx, s);
  }
  float se = 0.f, ws = 0.f;
  const float* bp = beta + l*kBV + b*kV;
#pragma unroll
  for (int v = 0; v < kV; v++){ float e = __expf(vals[v] - mx); se += e; ws = fmaf(e, bp[v], ws); }
  attn[idx] = ws / se;
}

// att_e[l][p] = attn[l][batch[s]][node_ids[s]], s = src_perm[p] (perm-ordered, all layers)
__global__ void att_e_kernel(const int* __restrict__ src_perm, const int* __restrict__ batch,
    const int* __restrict__ node_ids, const float* __restrict__ attn,
    float* __restrict__ att_e){
  int idx = blockIdx.x*256 + threadIdx.x;
  if (idx >= kL*kE) return;
  int l = idx / kE, p = idx - l*kE;
  int s = src_perm[p];
  att_e[idx] = attn[(size_t)l*kB*kNodes + (size_t)batch[s]*kNodes + node_ids[s]];
}

// ---------- GNN layer: fused aggregate + nn (512 threads = 8 waves, 8 nodes/block) ----------
// r13-proven version: 1 wave/node, 2-stage pipeline on the edge loop.

__global__ __launch_bounds__(512) void aggnn_kernel(const int* __restrict__ starts,
    const int* __restrict__ src_perm, const int* __restrict__ rel_perm,
    const float* __restrict__ att_e_l, const float* __restrict__ relterm_l,
    const unsigned short* __restrict__ xbf_in, unsigned short* __restrict__ xbf_out,
    float* __restrict__ x, const float* __restrict__ nn_wT_l, const float* __restrict__ nn_b_l){
  __shared__ float rows[8][kH];
  int t = threadIdx.x;
  int wv = t >> 6, lane = t & 63;
  int node = blockIdx.x*8 + wv;
  int p0 = starts[node], p1 = starts[node+1];
  int c = lane*2;
  float a0 = 0.f, a1 = 0.f;

  float at_c = 0.f;
  unsigned int xv_c = 0u;
  float2 rt_c = float2{0.f, 0.f};
  if (p0 < p1){
    int s0 = src_perm[p0], r0 = rel_perm[p0];
    at_c = att_e_l[p0];
    xv_c = *reinterpret_cast<const unsigned int*>(&xbf_in[(size_t)s0*kH + c]);
    rt_c = *reinterpret_cast<const float2*>(&relterm_l[(size_t)r0*kH + c]);
  }
  for (int p = p0; p < p1; p++){
    float at_n = 0.f;
    unsigned int xv_n = 0u;
    float2 rt_n = float2{0.f, 0.f};
    if (p + 1 < p1){
      int sn = src_perm[p+1], rn = rel_perm[p+1];
      at_n = att_e_l[p+1];
      xv_n = *reinterpret_cast<const unsigned int*>(&xbf_in[(size_t)sn*kH + c]);
      rt_n = *reinterpret_cast<const float2*>(&relterm_l[(size_t)rn*kH + c]);
    }
    float x0 = __uint_as_float(xv_c << 16);            // low bf16
    float x1 = __uint_as_float(xv_c & 0xFFFF0000u);    // high bf16
    float m0 = fmaf(x0, at_c, rt_c.x); m0 = m0 > 0.f ? m0 : 0.f;
    float m1 = fmaf(x1, at_c, rt_c.y); m1 = m1 > 0.f ? m1 : 0.f;
    a0 += m0; a1 += m1;
    at_c = at_n; xv_c = xv_n; rt_c = rt_n;
  }
  size_t gi = (size_t)node*kH + c;
  rows[wv][c]   = a0 + x[gi];
  rows[wv][c+1] = a1 + x[gi+1];
  __syncthreads();
  int cc = t & 127;
  int r0 = (t >> 7) * 2;                 // rows {0,1},{2,3},{4,5},{6,7}
  float acc0 = 0.f, acc1 = 0.f;
#pragma unroll 8
  for (int k = 0; k < kH; k++){
    float w = nn_wT_l[k*kH + cc];
    acc0 = fmaf(rows[r0  ][k], w, acc0);
    acc1 = fmaf(rows[r0+1][k], w, acc1);
  }
  float b = nn_b_l[cc];
  float o0 = fmaxf(acc0 + b, 0.f);
  float o1 = fmaxf(acc1 + b, 0.f);
  size_t n0 = (size_t)(blockIdx.x*8 + r0)*kH + cc;
  x[n0]        = o0;  xbf_out[n0]        = f2bf(o0);
  x[n0 + kH]   = o1;  xbf_out[n0 + kH]   = f2bf(o1);
}

// ---------- readout (fused; no atomics; HIGH PARALLELISM) ----------
// s<16: pool partial over 1/16 batch segment; s in [16,48): ehr*node_emb
// partial over 125 nodes. 1536 blocks total -> ~6 blocks/CU, latency hidden.
__global__ __launch_bounds__(128) void readprep_kernel(const float* __restrict__ x,
    const int* __restrict__ ub, const float* __restrict__ ehr,
    const float* __restrict__ node_emb, float* __restrict__ pp,
    float* __restrict__ pn, float* __restrict__ ps){
  int s = blockIdx.x, b = blockIdx.y, c = threadIdx.x;
  if (s < kPSeg){
    int lo = ub[b], len = ub[b+1] - lo;
    int i0 = lo + (int)(((long long)len * s) / kPSeg);
    int i1 = lo + (int)(((long long)len * (s+1)) / kPSeg);
    float acc = 0.f;
    for (int i = i0; i < i1; i++) acc += x[(size_t)i*kH + c];
    pp[(size_t)(b*kPSeg + s)*kH + c] = acc;
  } else {
    int q = s - kPSeg;                       // 0..31
    constexpr int seg = kNodes/kESeg;        // 125
    int n0 = q * seg;
    const float* ep = ehr + (size_t)b*kNodes + n0;
    const float* ne = node_emb + (size_t)n0*kH + c;
    float acc0 = 0.f, acc1 = 0.f, es = 0.f;
#pragma unroll 4
    for (int n = 0; n < seg - 1; n += 2){    // pairs (0,1)..(122,123)
      float e0 = ep[n], e1 = ep[n+1];
      es += e0 + e1;
      acc0 = fmaf(e0, ne[(size_t)n*kH], acc0);
      acc1 = fmaf(e1, ne[(size_t)(n+1)*kH], acc1);
    }
    {                                        // odd tail: n = 124 only
      float e0 = ep[seg - 1];
      es += e0;
      acc0 = fmaf(e0, ne[(size_t)(seg - 1)*kH], acc0);
    }
    pn[(size_t)(b*kESeg + q)*kH + c] = acc0 + acc1;
    if (c == 0) ps[b*kESeg + q] = es;
  }
}

// xg-finish + xnode-finish + final MLP in one kernel
__global__ __launch_bounds__(128) void readout_kernel(const float* __restrict__ pp,
    const int* __restrict__ ub, const float* __restrict__ pn, const float* __restrict__ ps,
    const float* __restrict__ lin_wT, const float* __restrict__ lin_b,
    const float* __restrict__ mlp_w, const float* __restrict__ mlp_b,
    float* __restrict__ out){
  int b = blockIdx.x, h = threadIdx.x;
  __shared__ float v[2*kH];
  __shared__ float ts[kH];
  float s = 0.f;
#pragma unroll
  for (int q = 0; q < kPSeg; q++) s += pp[(size_t)(b*kPSeg + q)*kH + h];
  int len = ub[b+1] - ub[b]; if (len < 1) len = 1;
  v[h] = s / (float)len;
  float acc = 0.f, es = 0.f;
#pragma unroll
  for (int q = 0; q < kESeg; q++){
    acc += pn[(size_t)(b*kESeg + q)*kH + h];
    es  += ps[b*kESeg + q];
  }
  ts[h] = acc / es;
  __syncthreads();
  float r = lin_b[h];
#pragma unroll 8
  for (int k = 0; k < kH; k++) r = fmaf(ts[k], lin_wT[k*kH + h], r);
  v[kH + h] = r;
  __syncthreads();
  float o = mlp_b[h];
#pragma unroll 8
  for (int k = 0; k < 2*kH; k++) o = fmaf(v[k], mlp_w[(size_t)h*2*kH + k], o);
  out[b*kH + h] = o;
}

} // namespace

extern "C" void kernel_launch(void* const* d_in, const int* in_sizes, int n_in,
                              void* d_out, int out_size, void* d_ws, size_t ws_size,
                              hipStream_t stream){
  const int*   node_ids = (const int*)d_in[0];
  const int*   rel_ids  = (const int*)d_in[1];
  const int*   e_src    = (const int*)d_in[2];
  const int*   e_dst    = e_src + kE;
  const int*   batch    = (const int*)d_in[3];
  const float* visit    = (const float*)d_in[4];
  const float* ehr      = (const float*)d_in[5];
  const float* node_emb = (const float*)d_in[6];
  const float* rel_emb  = (const float*)d_in[7];
  const float* lin_w    = (const float*)d_in[8];
  const float* lin_b    = (const float*)d_in[9];
  const float* alpha_w  = (const float*)d_in[10];
  const float* beta_w   = (const float*)d_in[12];
  const float* beta_b   = (const float*)d_in[13];
  const float* wr_w     = (const float*)d_in[14];
  const float* wr_b     = (const float*)d_in[15];
  const float* nn_w     = (const float*)d_in[16];
  const float* nn_b     = (const float*)d_in[17];
  const float* mlp_w    = (const float*)d_in[18];
  const float* mlp_b    = (const float*)d_in[19];
  float* out = (float*)d_out;

  char* w = (char*)d_ws;
  auto alloc = [&](size_t bytes)->char*{
    char* p = w; w += (bytes + 255) & ~(size_t)255; return p;
  };
  int*   starts = (int*)  alloc((size_t)(kN+1)*4);
  int*   deg    = (int*)  alloc((size_t)kN*4);
  int*   bsum   = (int*)  alloc(256*4);
  int*   ub     = (int*)  alloc((kB+1)*4);
  int*   src_perm = (int*)alloc((size_t)kE*4);
  int*   rel_perm = (int*)alloc((size_t)kE*4);
  unsigned short* rank = (unsigned short*)alloc((size_t)kE*2);
  unsigned int* hpart  = (unsigned int*)alloc((size_t)kNB*kN*4);   // becomes colOff in place
  float* embLin = (float*)alloc((size_t)kNodes*kH*4);
  float* relLin = (float*)alloc((size_t)kRels*kH*4);
  float* relterm= (float*)alloc((size_t)kL*kRels*kH*4);
  float* linwT  = (float*)alloc((size_t)kH*kH*4);
  float* nnwT   = (float*)alloc((size_t)kL*kH*kH*4);
  float* x      = (float*)alloc((size_t)kN*kH*4);
  unsigned short* xbfA = (unsigned short*)alloc((size_t)kN*kH*2);
  unsigned short* xbfB = (unsigned short*)alloc((size_t)kN*kH*2);
  unsigned short* visitbf = (unsigned short*)alloc((size_t)kBV*kKW*2);
  unsigned short* awbf    = (unsigned short*)alloc((size_t)kL*kMPad*kKW*2);
  unsigned short* S       = (unsigned short*)alloc((size_t)kL*2*kBV*kMPad*2);
  float* attn   = (float*)alloc((size_t)kL*kB*kNodes*4);
  float* att_e  = (float*)alloc((size_t)kL*kE*4);
  float* beta   = (float*)alloc((size_t)kL*kBV*4);
  float* pp     = (float*)alloc((size_t)kB*kPSeg*kH*4);
  float* pn     = (float*)alloc((size_t)kB*kESeg*kH*4);
  float* ps     = (float*)alloc((size_t)kB*kESeg*4);
  if ((size_t)(w - (char*)d_ws) > ws_size) return;   // ws too small: fail visibly

  // prep
  transpose_kernel<<<4, 256, 0, stream>>>(lin_w, nn_w, linwT, nnwT);
  proj_kernel<<<kNodes + kRels, 128, 0, stream>>>(node_emb, rel_emb, linwT, lin_b, embLin, relLin);
  gather_x0_kernel<<<(kN*kH)/256, 256, 0, stream>>>(node_ids, embLin, x, xbfA);
  relterm_kernel<<<kL*kRels, 128, 0, stream>>>(relLin, wr_w, wr_b, relterm);

  // CSR build (no global atomics)
  csr_hist_kernel<<<dim3(kNB, 2), 256, 0, stream>>>(e_dst, rank, hpart);
  csr_col_kernel<<<(kN+255)/256, 256, 0, stream>>>(hpart, deg);
  scanA_kernel<<<(kN+255)/256, 256, 0, stream>>>(deg, starts, bsum);
  scanC_kernel<<<(kN+255)/256, 256, 0, stream>>>(starts, bsum, (kN+255)/256);
  csr_place_kernel<<<128, 256, 0, stream>>>(e_dst, e_src, rel_ids, starts, hpart, rank,
                                            src_perm, rel_perm);
  ub_kernel<<<1, 64, 0, stream>>>(batch, ub);

  // attention path (all layers batched)
  visit_prep_kernel<<<kBV, 256, 0, stream>>>(visit, beta_w, beta_b, visitbf, beta);
  cvtW_kernel<<<(kL*kMPad*(kKW/8) + 255)/256, 256, 0, stream>>>(alpha_w, awbf);
  gemm_bt_bf16<<<960, 256, 0, stream>>>(visitbf, awbf, S);
  attn_kernel<<<(kL*kB*kNodes + 255)/256, 256, 0, stream>>>(S, beta, attn);
  att_e_kernel<<<(kL*kE + 255)/256, 256, 0, stream>>>(src_perm, batch, node_ids, attn, att_e);

  // GNN layers (fused aggregate+nn; xbf ping-pong, x f32 block-local in-place)
  unsigned short* xin = xbfA;
  unsigned short* xout = xbfB;
  for (int l = 0; l < kL; l++){
    aggnn_kernel<<<kN/8, 512, 0, stream>>>(starts, src_perm, rel_perm,
        att_e + (size_t)l*kE, relterm + (size_t)l*kRels*kH,
        xin, xout, x, nnwT + (size_t)l*kH*kH, nn_b + (size_t)l*kH);
    unsigned short* tmp = xin; xin = xout; xout = tmp;
  }

  // readout
  readprep_kernel<<<dim3(kPSeg + kESeg, kB), 128, 0, stream>>>(x, ub, ehr, node_emb, pp, pn, ps);
  readout_kernel<<<kB, 128, 0, stream>>>(pp, ub, pn, ps, linwT, lin_b, mlp_w, mlp_b, out);
}

// Round 19
// 507.075 us; speedup vs baseline: 1.0529x; 1.0207x over previous
//
#include <hip/hip_runtime.h>

namespace {

constexpr int kNodes = 4000;        // node-TYPE vocabulary (attn/alpha space)
constexpr int kRels  = 400;
constexpr int kB     = 32;
constexpr int kV     = 20;
constexpr int kN     = 32000;       // graph nodes (CSR space)
constexpr int kE     = 256000;
constexpr int kH     = 128;
constexpr int kL     = 3;
constexpr int kMPad  = 4096;        // alpha_w m-dim padded (output tiling)
constexpr int kKW    = 4000;        // K exact: 125 x BK=32
constexpr int kBV    = kB * kV;     // 640
constexpr int kNB    = 32;          // CSR sort blocks
constexpr int kChunk = kE / kNB;    // 8000 edges per sort block
constexpr int kHalf  = 16000;       // bins per LDS pass (64KB LDS); 2*kHalf == kN
constexpr int kPSeg  = 16;          // pool segments per batch
constexpr int kESeg  = 32;          // ehr segments per batch (125 nodes each)

typedef __attribute__((ext_vector_type(8))) short bf16x8;
typedef __attribute__((ext_vector_type(4))) float f32x4;

__device__ inline unsigned short f2bf(float f){
  unsigned int u = __float_as_uint(f);
  u += 0x7FFFu + ((u >> 16) & 1u);      // round-to-nearest-even
  return (unsigned short)(u >> 16);
}
__device__ inline float bf2f(unsigned short u){
  return __uint_as_float(((unsigned int)u) << 16);
}

// global->LDS direct copy, 16B per lane, dest = wave-uniform base + lane*16
__device__ inline void gload_lds16(const unsigned short* g, unsigned short* l){
  __builtin_amdgcn_global_load_lds(
      (const __attribute__((address_space(1))) unsigned int*)(g),
      (__attribute__((address_space(3))) unsigned int*)(l),
      16, 0, 0);
}

// ---------- prep kernels ----------

__global__ void transpose_kernel(const float* __restrict__ lin_w, const float* __restrict__ nn_w,
                                 float* __restrict__ lin_wT, float* __restrict__ nn_wT){
  int m = blockIdx.x;
  const float* in = (m == 0) ? lin_w : nn_w + (size_t)(m-1)*kH*kH;
  float* out      = (m == 0) ? lin_wT : nn_wT + (size_t)(m-1)*kH*kH;
  for (int i = threadIdx.x; i < kH*kH; i += blockDim.x){
    int r = i >> 7, c = i & (kH-1);
    out[c*kH + r] = in[i];
  }
}

__global__ __launch_bounds__(128) void proj_kernel(const float* __restrict__ node_emb,
    const float* __restrict__ rel_emb, const float* __restrict__ lin_wT,
    const float* __restrict__ lin_b, float* __restrict__ emb_lin, float* __restrict__ rel_lin){
  int row = blockIdx.x;
  const float* src; float* dst;
  if (row < kNodes){ src = node_emb + (size_t)row*kH; dst = emb_lin + (size_t)row*kH; }
  else             { src = rel_emb + (size_t)(row-kNodes)*kH; dst = rel_lin + (size_t)(row-kNodes)*kH; }
  __shared__ float rs[kH];
  int h = threadIdx.x;
  rs[h] = src[h];
  __syncthreads();
  float acc = lin_b[h];
#pragma unroll 8
  for (int k = 0; k < kH; k++) acc = fmaf(rs[k], lin_wT[k*kH + h], acc);
  dst[h] = acc;
}

__global__ void gather_x0_kernel(const int* __restrict__ node_ids,
                                 const float* __restrict__ emb_lin, float* __restrict__ x,
                                 unsigned short* __restrict__ xbf){
  int idx = blockIdx.x*256 + threadIdx.x;
  if (idx < kN*kH){
    int i = idx >> 7, c = idx & (kH-1);
    float v = emb_lin[(size_t)node_ids[i]*kH + c];
    x[idx] = v;
    xbf[idx] = f2bf(v);
  }
}

// relterm stored as bf16: halves per-edge rt load and L2 footprint
__global__ __launch_bounds__(128) void relterm_kernel(const float* __restrict__ rel_lin,
    const float* __restrict__ wr_w, const float* __restrict__ wr_b,
    unsigned short* __restrict__ relterm){
  int l = blockIdx.x / kRels, r = blockIdx.x % kRels;
  int t = threadIdx.x;
  float rl = rel_lin[(size_t)r*kH + t];
  __shared__ float red[kH];
  red[t] = rl * wr_w[l*kH + t];
  __syncthreads();
  for (int o = 64; o > 0; o >>= 1){
    if (t < o) red[t] += red[t+o];
    __syncthreads();
  }
  float w = red[0] + wr_b[l];
  relterm[((size_t)l*kRels + r)*kH + t] = f2bf(w * rl);
}

// ---------- CSR build over kN graph nodes (no global atomics) ----------

__global__ __launch_bounds__(256) void csr_hist_kernel(const int* __restrict__ dst,
    unsigned short* __restrict__ rank, unsigned int* __restrict__ hpart){
  __shared__ unsigned int hb[kHalf];
  int p = blockIdx.x;
  int base = blockIdx.y * kHalf;
  int t = threadIdx.x;
  for (int i = t; i < kHalf; i += 256) hb[i] = 0u;
  __syncthreads();
  for (int i = t; i < kChunk; i += 256){
    int e = p*kChunk + i;
    int d = dst[e];
    int rel = d - base;
    if ((unsigned)rel < (unsigned)kHalf){
      rank[e] = (unsigned short)atomicAdd(&hb[rel], 1u);
    }
  }
  __syncthreads();
  for (int i = t; i < kHalf; i += 256)
    hpart[(size_t)p*kN + base + i] = hb[i];
}

__global__ __launch_bounds__(256) void csr_col_kernel(unsigned int* __restrict__ hpart,
    int* __restrict__ deg){
  int bin = blockIdx.x*256 + threadIdx.x;
  if (bin >= kN) return;
  unsigned int s = 0;
#pragma unroll
  for (int p = 0; p < kNB; p++){
    size_t idx = (size_t)p*kN + bin;
    unsigned int v = hpart[idx];
    hpart[idx] = s;
    s += v;
  }
  deg[bin] = (int)s;
}

__global__ __launch_bounds__(256) void scanA_kernel(const int* __restrict__ deg,
    int* __restrict__ starts, int* __restrict__ bsum){
  __shared__ int buf[256];
  int gid = blockIdx.x*256 + threadIdx.x;
  int t = threadIdx.x;
  int v = (gid < kN) ? deg[gid] : 0;
  buf[t] = v;
  __syncthreads();
  for (int o = 1; o < 256; o <<= 1){
    int add = (t >= o) ? buf[t-o] : 0;
    __syncthreads();
    buf[t] += add;
    __syncthreads();
  }
  if (gid < kN) starts[gid] = buf[t] - v;
  if (t == 255) bsum[blockIdx.x] = buf[255];
}

// fused scanB+scanC: every block re-scans bsum in LDS, adds its own prefix
__global__ __launch_bounds__(256) void scanC_kernel(int* __restrict__ starts,
    const int* __restrict__ bsum, int nblk){
  __shared__ int buf[128];
  int t = threadIdx.x;
  if (t < 128){
    int v = (t < nblk) ? bsum[t] : 0;
    buf[t] = v;
  }
  __syncthreads();
  for (int o = 1; o < 128; o <<= 1){
    int add = 0;
    if (t < 128 && t >= o) add = buf[t-o];
    __syncthreads();
    if (t < 128) buf[t] += add;
    __syncthreads();
  }
  int boff = (blockIdx.x > 0) ? buf[blockIdx.x - 1] : 0;   // exclusive prefix
  int gid = blockIdx.x*256 + t;
  if (gid < kN) starts[gid] += boff;
  if (gid == kN-1) starts[kN] = kE;
}

// writes packed (src | rel<<15) per edge in CSR order: src<32768, rel<512
__global__ __launch_bounds__(256) void csr_place_kernel(const int* __restrict__ dst,
    const int* __restrict__ src, const int* __restrict__ rel_ids,
    const int* __restrict__ starts, const unsigned int* __restrict__ colOff,
    const unsigned short* __restrict__ rank, int* __restrict__ epack){
  int blk = blockIdx.x;                 // 128 blocks x 2000 edges
  int p = blk >> 2;                     // 4 blocks per sort chunk
  for (int i = threadIdx.x; i < 2000; i += 256){
    int e = blk*2000 + i;
    int d = dst[e];
    int pos = starts[d] + (int)colOff[(size_t)p*kN + d] + (int)rank[e];
    epack[pos] = src[e] | (rel_ids[e] << 15);
  }
}

__global__ void ub_kernel(const int* __restrict__ batch, int* __restrict__ ub){
  int j = threadIdx.x;
  if (j > kB) return;
  int lo = 0, hi = kN;
  while (lo < hi){
    int mid = (lo + hi) >> 1;
    if (batch[mid] < j) lo = mid + 1; else hi = mid;
  }
  ub[j] = lo;
}

// ---------- attention path ----------

// fused: visit row -> bf16 row + all 3 layers' beta dot products (visit read ONCE)
__global__ __launch_bounds__(256) void visit_prep_kernel(const float* __restrict__ visit,
    const float* __restrict__ beta_w, const float* __restrict__ beta_b,
    unsigned short* __restrict__ visitbf, float* __restrict__ beta){
  int bv = blockIdx.x;
  int t = threadIdx.x;
  const float* row = visit + (size_t)bv*kKW;
  unsigned short* outr = visitbf + (size_t)bv*kKW;
  float d0 = 0.f, d1 = 0.f, d2 = 0.f;
  for (int i = t; i < kKW/4; i += 256){
    float4 v = *reinterpret_cast<const float4*>(row + i*4);
    unsigned int lo = ((unsigned int)f2bf(v.y) << 16) | f2bf(v.x);
    unsigned int hi = ((unsigned int)f2bf(v.w) << 16) | f2bf(v.z);
    *reinterpret_cast<uint2*>(outr + i*4) = uint2{lo, hi};
    float4 w0 = *reinterpret_cast<const float4*>(beta_w + i*4);
    float4 w1 = *reinterpret_cast<const float4*>(beta_w + kKW + i*4);
    float4 w2 = *reinterpret_cast<const float4*>(beta_w + 2*kKW + i*4);
    d0 = fmaf(v.x,w0.x, fmaf(v.y,w0.y, fmaf(v.z,w0.z, fmaf(v.w,w0.w, d0))));
    d1 = fmaf(v.x,w1.x, fmaf(v.y,w1.y, fmaf(v.z,w1.z, fmaf(v.w,w1.w, d1))));
    d2 = fmaf(v.x,w2.x, fmaf(v.y,w2.y, fmaf(v.z,w2.z, fmaf(v.w,w2.w, d2))));
  }
#pragma unroll
  for (int o = 32; o > 0; o >>= 1){
    d0 += __shfl_down(d0, o);
    d1 += __shfl_down(d1, o);
    d2 += __shfl_down(d2, o);
  }
  __shared__ float part[3][4];
  int wv = t >> 6, ln = t & 63;
  if (ln == 0){ part[0][wv] = d0; part[1][wv] = d1; part[2][wv] = d2; }
  __syncthreads();
  if (t < 3){
    float s = part[t][0] + part[t][1] + part[t][2] + part[t][3];
    int v = bv % kV;
    float lam = __expf(0.03f * (float)(kV - v));
    beta[t*kBV + bv] = tanhf(s + beta_b[t]) * lam;
  }
}

// all 3 layers of alpha_w (4000x4000 f32) -> (4096 x 4000 bf16), pad rows zeroed
__global__ void cvtW_kernel(const float* __restrict__ W, unsigned short* __restrict__ out){
  int i = blockIdx.x*256 + threadIdx.x;
  constexpr int perL = kMPad*(kKW/8);
  if (i >= kL*perL) return;
  int l = i / perL;
  int rem = i - l*perL;
  int row = rem / (kKW/8);
  int col = (rem - row*(kKW/8)) * 8;
  unsigned short r[8];
  if (row < kNodes){
    const float* p = W + (size_t)l*kNodes*kNodes + (size_t)row*kKW + col;
    const float4 a = *reinterpret_cast<const float4*>(p);
    const float4 b = *reinterpret_cast<const float4*>(p + 4);
    r[0]=f2bf(a.x); r[1]=f2bf(a.y); r[2]=f2bf(a.z); r[3]=f2bf(a.w);
    r[4]=f2bf(b.x); r[5]=f2bf(b.y); r[6]=f2bf(b.z); r[7]=f2bf(b.w);
  } else {
    for (int q = 0; q < 8; q++) r[q] = 0;
  }
  *reinterpret_cast<uint4*>(out + (size_t)l*kMPad*kKW + (size_t)row*kKW + col)
      = *reinterpret_cast<uint4*>(r);
}

// S[lz](640 x 4096, bf16) = A(640 x Kslice) @ B_l(4096 x Kslice)^T ; lz = l*2+z
// r16-proven structure (107-110us, total 517): BK=32 double-buffer, depth-1
// prefetch, 0-conflict both-sides swizzle, XCD-chunked block swizzle; bf16 C.
__global__ __launch_bounds__(256) void gemm_bt_bf16(const unsigned short* __restrict__ A,
    const unsigned short* __restrict__ Ball, unsigned short* __restrict__ Sbase){
  __shared__ unsigned short As[2][128*32];
  __shared__ unsigned short Bs[2][128*32];
  // 960 blocks; chunk = 120 per XCD
  int wg = (blockIdx.x & 7)*120 + (blockIdx.x >> 3);
  int lz = wg / 160;
  int rem = wg - lz*160;
  int bn = rem / 5;
  int bm = rem - bn*5;
  int l = lz >> 1, z = lz & 1;
  const unsigned short* B = Ball + (size_t)l*kMPad*kKW;
  unsigned short* C = Sbase + (size_t)lz*kBV*kMPad;
  int tile0 = z ? 63 : 0;               // 125 tiles total: 63 + 62
  int nt    = z ? 62 : 63;

  int t = threadIdx.x;
  int lane = t & 63, wave = t >> 6;
  int wm = (wave >> 1) * 64, wn = (wave & 1) * 64;
  int r = lane & 15, g = lane >> 4;

  int ri = lane >> 2, s = lane & 3;
  int koff = ((s ^ ((ri >> 1) & 3)) << 3);   // elements
  const unsigned short* Ag = A + (size_t)(bm*128 + wave*32 + ri)*kKW + tile0*32 + koff;
  const unsigned short* Bg = B + (size_t)(bn*128 + wave*32 + ri)*kKW + tile0*32 + koff;
  const size_t rstep = (size_t)16*kKW;       // 16 rows

  f32x4 acc[4][4];
#pragma unroll
  for (int i = 0; i < 4; i++)
#pragma unroll
    for (int j = 0; j < 4; j++) acc[i][j] = f32x4{0.f,0.f,0.f,0.f};

  auto STAGE = [&](int buf, int ts){
    const unsigned short* a = Ag + ts*32;
    const unsigned short* b = Bg + ts*32;
    gload_lds16(a,         &As[buf][(wave*32     )*32]);
    gload_lds16(a + rstep, &As[buf][(wave*32 + 16)*32]);
    gload_lds16(b,         &Bs[buf][(wave*32     )*32]);
    gload_lds16(b + rstep, &Bs[buf][(wave*32 + 16)*32]);
  };

  STAGE(0, 0);
  for (int ts = 0; ts < nt; ts++){
    int cur = ts & 1;
    __syncthreads();                   // drains vmcnt: STAGE(ts) landed for all waves
    if (ts + 1 < nt) STAGE(cur ^ 1, ts + 1);   // prefetch overlaps this tile's compute
    bf16x8 af[4], bf[4];
#pragma unroll
    for (int i = 0; i < 4; i++){
      int arow = wm + i*16 + r;
      int brow = wn + i*16 + r;
      af[i] = *reinterpret_cast<const bf16x8*>(
          &As[cur][arow*32 + ((g ^ ((arow >> 1) & 3)) << 3)]);
      bf[i] = *reinterpret_cast<const bf16x8*>(
          &Bs[cur][brow*32 + ((g ^ ((brow >> 1) & 3)) << 3)]);
    }
#pragma unroll
    for (int i = 0; i < 4; i++)
#pragma unroll
      for (int j = 0; j < 4; j++)
        acc[i][j] = __builtin_amdgcn_mfma_f32_16x16x32_bf16(af[i], bf[j], acc[i][j], 0, 0, 0);
  }
#pragma unroll
  for (int i = 0; i < 4; i++)
#pragma unroll
    for (int j = 0; j < 4; j++){
      int row = bm*128 + wm + i*16 + g*4;
      int col = bn*128 + wn + j*16 + r;
#pragma unroll
      for (int q = 0; q < 4; q++)
        C[(size_t)(row + q)*kMPad + col] = f2bf(acc[i][j][q]);
    }
}

// attn[l][b][m] = sum_v softmax_v(S0+S1) * beta[l,b,v]  (all layers; S is bf16)
__global__ __launch_bounds__(256) void attn_kernel(const unsigned short* __restrict__ S,
    const float* __restrict__ beta, float* __restrict__ attn){
  int idx = blockIdx.x*256 + threadIdx.x;
  if (idx >= kL*kB*kNodes) return;
  int l = idx / (kB*kNodes);
  int rem = idx - l*(kB*kNodes);
  int b = rem / kNodes;
  int m = rem - b*kNodes;
  const unsigned short* S0 = S + (size_t)(l*2)*kBV*kMPad + (size_t)b*kV*kMPad + m;
  const unsigned short* S1 = S0 + (size_t)kBV*kMPad;
  float vals[kV];
  float mx = -1e30f;
#pragma unroll
  for (int v = 0; v < kV; v++){
    float s = bf2f(S0[(size_t)v*kMPad]) + bf2f(S1[(size_t)v*kMPad]);
    vals[v] = s; mx = fmaxf(mx, s);
  }
  float se = 0.f, ws = 0.f;
  const float* bp = beta + l*kBV + b*kV;
#pragma unroll
  for (int v = 0; v < kV; v++){ float e = __expf(vals[v] - mx); se += e; ws = fmaf(e, bp[v], ws); }
  attn[idx] = ws / se;
}

// edat[l][p] = {att_e bits, packed src|rel}: ONE 8B broadcast load per edge in aggnn
__global__ void edat_kernel(const int* __restrict__ epack, const int* __restrict__ batch,
    const int* __restrict__ node_ids, const float* __restrict__ attn,
    uint2* __restrict__ edat){
  int idx = blockIdx.x*256 + threadIdx.x;
  if (idx >= kL*kE) return;
  int l = idx / kE, p = idx - l*kE;
  int pk = epack[p];
  int s = pk & 0x7FFF;
  float at = attn[(size_t)l*kB*kNodes + (size_t)batch[s]*kNodes + node_ids[s]];
  edat[idx] = uint2{__float_as_uint(at), (unsigned int)pk};
}

// ---------- GNN layer: fused aggregate + nn (512 threads = 8 waves, 8 nodes/block) ----------
// r13 pipeline + packed edge header (1 load) + bf16 relterm (4B rt load).

__global__ __launch_bounds__(512) void aggnn_kernel(const int* __restrict__ starts,
    const uint2* __restrict__ edat_l, const unsigned short* __restrict__ relterm_l,
    const unsigned short* __restrict__ xbf_in, unsigned short* __restrict__ xbf_out,
    float* __restrict__ x, const float* __restrict__ nn_wT_l, const float* __restrict__ nn_b_l){
  __shared__ float rows[8][kH];
  int t = threadIdx.x;
  int wv = t >> 6, lane = t & 63;
  int node = blockIdx.x*8 + wv;
  int p0 = starts[node], p1 = starts[node+1];
  int c = lane*2;
  float a0 = 0.f, a1 = 0.f;

  float at_c = 0.f;
  unsigned int xv_c = 0u, rw_c = 0u;
  if (p0 < p1){
    uint2 ed = edat_l[p0];
    at_c = __uint_as_float(ed.x);
    int s0 = (int)(ed.y & 0x7FFFu);
    int r0 = (int)(ed.y >> 15);
    xv_c = *reinterpret_cast<const unsigned int*>(&xbf_in[(size_t)s0*kH + c]);
    rw_c = *reinterpret_cast<const unsigned int*>(&relterm_l[(size_t)r0*kH + c]);
  }
  for (int p = p0; p < p1; p++){
    float at_n = 0.f;
    unsigned int xv_n = 0u, rw_n = 0u;
    if (p + 1 < p1){
      uint2 ed = edat_l[p+1];
      at_n = __uint_as_float(ed.x);
      int sn = (int)(ed.y & 0x7FFFu);
      int rn = (int)(ed.y >> 15);
      xv_n = *reinterpret_cast<const unsigned int*>(&xbf_in[(size_t)sn*kH + c]);
      rw_n = *reinterpret_cast<const unsigned int*>(&relterm_l[(size_t)rn*kH + c]);
    }
    float x0 = __uint_as_float(xv_c << 16);            // low bf16
    float x1 = __uint_as_float(xv_c & 0xFFFF0000u);    // high bf16
    float r0 = __uint_as_float(rw_c << 16);
    float r1 = __uint_as_float(rw_c & 0xFFFF0000u);
    float m0 = fmaf(x0, at_c, r0); m0 = m0 > 0.f ? m0 : 0.f;
    float m1 = fmaf(x1, at_c, r1); m1 = m1 > 0.f ? m1 : 0.f;
    a0 += m0; a1 += m1;
    at_c = at_n; xv_c = xv_n; rw_c = rw_n;
  }
  size_t gi = (size_t)node*kH + c;
  rows[wv][c]   = a0 + x[gi];
  rows[wv][c+1] = a1 + x[gi+1];
  __syncthreads();
  int cc = t & 127;
  int r0 = (t >> 7) * 2;                 // rows {0,1},{2,3},{4,5},{6,7}
  float acc0 = 0.f, acc1 = 0.f;
#pragma unroll 8
  for (int k = 0; k < kH; k++){
    float w = nn_wT_l[k*kH + cc];
    acc0 = fmaf(rows[r0  ][k], w, acc0);
    acc1 = fmaf(rows[r0+1][k], w, acc1);
  }
  float b = nn_b_l[cc];
  float o0 = fmaxf(acc0 + b, 0.f);
  float o1 = fmaxf(acc1 + b, 0.f);
  size_t n0 = (size_t)(blockIdx.x*8 + r0)*kH + cc;
  x[n0]        = o0;  xbf_out[n0]        = f2bf(o0);
  x[n0 + kH]   = o1;  xbf_out[n0 + kH]   = f2bf(o1);
}

// ---------- readout (fused; no atomics; HIGH PARALLELISM) ----------
__global__ __launch_bounds__(128) void readprep_kernel(const float* __restrict__ x,
    const int* __restrict__ ub, const float* __restrict__ ehr,
    const float* __restrict__ node_emb, float* __restrict__ pp,
    float* __restrict__ pn, float* __restrict__ ps){
  int s = blockIdx.x, b = blockIdx.y, c = threadIdx.x;
  if (s < kPSeg){
    int lo = ub[b], len = ub[b+1] - lo;
    int i0 = lo + (int)(((long long)len * s) / kPSeg);
    int i1 = lo + (int)(((long long)len * (s+1)) / kPSeg);
    float acc = 0.f;
    for (int i = i0; i < i1; i++) acc += x[(size_t)i*kH + c];
    pp[(size_t)(b*kPSeg + s)*kH + c] = acc;
  } else {
    int q = s - kPSeg;                       // 0..31
    constexpr int seg = kNodes/kESeg;        // 125
    int n0 = q * seg;
    const float* ep = ehr + (size_t)b*kNodes + n0;
    const float* ne = node_emb + (size_t)n0*kH + c;
    float acc0 = 0.f, acc1 = 0.f, es = 0.f;
#pragma unroll 4
    for (int n = 0; n < seg - 1; n += 2){    // pairs (0,1)..(122,123)
      float e0 = ep[n], e1 = ep[n+1];
      es += e0 + e1;
      acc0 = fmaf(e0, ne[(size_t)n*kH], acc0);
      acc1 = fmaf(e1, ne[(size_t)(n+1)*kH], acc1);
    }
    {                                        // odd tail: n = 124 only
      float e0 = ep[seg - 1];
      es += e0;
      acc0 = fmaf(e0, ne[(size_t)(seg - 1)*kH], acc0);
    }
    pn[(size_t)(b*kESeg + q)*kH + c] = acc0 + acc1;
    if (c == 0) ps[b*kESeg + q] = es;
  }
}

// xg-finish + xnode-finish + final MLP in one kernel
__global__ __launch_bounds__(128) void readout_kernel(const float* __restrict__ pp,
    const int* __restrict__ ub, const float* __restrict__ pn, const float* __restrict__ ps,
    const float* __restrict__ lin_wT, const float* __restrict__ lin_b,
    const float* __restrict__ mlp_w, const float* __restrict__ mlp_b,
    float* __restrict__ out){
  int b = blockIdx.x, h = threadIdx.x;
  __shared__ float v[2*kH];
  __shared__ float ts[kH];
  float s = 0.f;
#pragma unroll
  for (int q = 0; q < kPSeg; q++) s += pp[(size_t)(b*kPSeg + q)*kH + h];
  int len = ub[b+1] - ub[b]; if (len < 1) len = 1;
  v[h] = s / (float)len;
  float acc = 0.f, es = 0.f;
#pragma unroll
  for (int q = 0; q < kESeg; q++){
    acc += pn[(size_t)(b*kESeg + q)*kH + h];
    es  += ps[b*kESeg + q];
  }
  ts[h] = acc / es;
  __syncthreads();
  float r = lin_b[h];
#pragma unroll 8
  for (int k = 0; k < kH; k++) r = fmaf(ts[k], lin_wT[k*kH + h], r);
  v[kH + h] = r;
  __syncthreads();
  float o = mlp_b[h];
#pragma unroll 8
  for (int k = 0; k < 2*kH; k++) o = fmaf(v[k], mlp_w[(size_t)h*2*kH + k], o);
  out[b*kH + h] = o;
}

} // namespace

extern "C" void kernel_launch(void* const* d_in, const int* in_sizes, int n_in,
                              void* d_out, int out_size, void* d_ws, size_t ws_size,
                              hipStream_t stream){
  const int*   node_ids = (const int*)d_in[0];
  const int*   rel_ids  = (const int*)d_in[1];
  const int*   e_src    = (const int*)d_in[2];
  const int*   e_dst    = e_src + kE;
  const int*   batch    = (const int*)d_in[3];
  const float* visit    = (const float*)d_in[4];
  const float* ehr      = (const float*)d_in[5];
  const float* node_emb = (const float*)d_in[6];
  const float* rel_emb  = (const float*)d_in[7];
  const float* lin_w    = (const float*)d_in[8];
  const float* lin_b    = (const float*)d_in[9];
  const float* alpha_w  = (const float*)d_in[10];
  const float* beta_w   = (const float*)d_in[12];
  const float* beta_b   = (const float*)d_in[13];
  const float* wr_w     = (const float*)d_in[14];
  const float* wr_b     = (const float*)d_in[15];
  const float* nn_w     = (const float*)d_in[16];
  const float* nn_b     = (const float*)d_in[17];
  const float* mlp_w    = (const float*)d_in[18];
  const float* mlp_b    = (const float*)d_in[19];
  float* out = (float*)d_out;

  char* w = (char*)d_ws;
  auto alloc = [&](size_t bytes)->char*{
    char* p = w; w += (bytes + 255) & ~(size_t)255; return p;
  };
  int*   starts = (int*)  alloc((size_t)(kN+1)*4);
  int*   deg    = (int*)  alloc((size_t)kN*4);
  int*   bsum   = (int*)  alloc(256*4);
  int*   ub     = (int*)  alloc((kB+1)*4);
  int*   epack  = (int*)  alloc((size_t)kE*4);
  unsigned short* rank = (unsigned short*)alloc((size_t)kE*2);
  unsigned int* hpart  = (unsigned int*)alloc((size_t)kNB*kN*4);   // becomes colOff in place
  float* embLin = (float*)alloc((size_t)kNodes*kH*4);
  float* relLin = (float*)alloc((size_t)kRels*kH*4);
  unsigned short* relterm = (unsigned short*)alloc((size_t)kL*kRels*kH*2);
  float* linwT  = (float*)alloc((size_t)kH*kH*4);
  float* nnwT   = (float*)alloc((size_t)kL*kH*kH*4);
  float* x      = (float*)alloc((size_t)kN*kH*4);
  unsigned short* xbfA = (unsigned short*)alloc((size_t)kN*kH*2);
  unsigned short* xbfB = (unsigned short*)alloc((size_t)kN*kH*2);
  unsigned short* visitbf = (unsigned short*)alloc((size_t)kBV*kKW*2);
  unsigned short* awbf    = (unsigned short*)alloc((size_t)kL*kMPad*kKW*2);
  unsigned short* S       = (unsigned short*)alloc((size_t)kL*2*kBV*kMPad*2);
  float* attn   = (float*)alloc((size_t)kL*kB*kNodes*4);
  uint2* edat   = (uint2*)alloc((size_t)kL*kE*8);
  float* beta   = (float*)alloc((size_t)kL*kBV*4);
  float* pp     = (float*)alloc((size_t)kB*kPSeg*kH*4);
  float* pn     = (float*)alloc((size_t)kB*kESeg*kH*4);
  float* ps     = (float*)alloc((size_t)kB*kESeg*4);
  if ((size_t)(w - (char*)d_ws) > ws_size) return;   // ws too small: fail visibly

  // prep
  transpose_kernel<<<4, 256, 0, stream>>>(lin_w, nn_w, linwT, nnwT);
  proj_kernel<<<kNodes + kRels, 128, 0, stream>>>(node_emb, rel_emb, linwT, lin_b, embLin, relLin);
  gather_x0_kernel<<<(kN*kH)/256, 256, 0, stream>>>(node_ids, embLin, x, xbfA);
  relterm_kernel<<<kL*kRels, 128, 0, stream>>>(relLin, wr_w, wr_b, relterm);

  // CSR build (no global atomics)
  csr_hist_kernel<<<dim3(kNB, 2), 256, 0, stream>>>(e_dst, rank, hpart);
  csr_col_kernel<<<(kN+255)/256, 256, 0, stream>>>(hpart, deg);
  scanA_kernel<<<(kN+255)/256, 256, 0, stream>>>(deg, starts, bsum);
  scanC_kernel<<<(kN+255)/256, 256, 0, stream>>>(starts, bsum, (kN+255)/256);
  csr_place_kernel<<<128, 256, 0, stream>>>(e_dst, e_src, rel_ids, starts, hpart, rank, epack);
  ub_kernel<<<1, 64, 0, stream>>>(batch, ub);

  // attention path (all layers batched)
  visit_prep_kernel<<<kBV, 256, 0, stream>>>(visit, beta_w, beta_b, visitbf, beta);
  cvtW_kernel<<<(kL*kMPad*(kKW/8) + 255)/256, 256, 0, stream>>>(alpha_w, awbf);
  gemm_bt_bf16<<<960, 256, 0, stream>>>(visitbf, awbf, S);
  attn_kernel<<<(kL*kB*kNodes + 255)/256, 256, 0, stream>>>(S, beta, attn);
  edat_kernel<<<(kL*kE + 255)/256, 256, 0, stream>>>(epack, batch, node_ids, attn, edat);

  // GNN layers (fused aggregate+nn; xbf ping-pong, x f32 block-local in-place)
  unsigned short* xin = xbfA;
  unsigned short* xout = xbfB;
  for (int l = 0; l < kL; l++){
    aggnn_kernel<<<kN/8, 512, 0, stream>>>(starts,
        edat + (size_t)l*kE, relterm + (size_t)l*kRels*kH,
        xin, xout, x, nnwT + (size_t)l*kH*kH, nn_b + (size_t)l*kH);
    unsigned short* tmp = xin; xin = xout; xout = tmp;
  }

  // readout
  readprep_kernel<<<dim3(kPSeg + kESeg, kB), 128, 0, stream>>>(x, ub, ehr, node_emb, pp, pn, ps);
  readout_kernel<<<kB, 128, 0, stream>>>(pp, ub, pn, ps, linwT, lin_b, mlp_w, mlp_b, out);
}